// Round 1
// baseline (533.686 us; speedup 1.0000x reference)
//
#include <hip/hip_runtime.h>
#include <hip/hip_bf16.h>

// SubGroupPooler: Z[t, s*D + d] = max_{g in team s} P[idx[s][g], t, d]
// N=12 players, T=4096 frames, D=2048 dims, 2 teams x 6 players.
// Memory-bound: 402.7 MB read + 67.1 MB write -> ~75 us floor at 6.3 TB/s.

constexpr int T_FRAMES = 4096;
constexpr int D_DIM    = 2048;
constexpr int N_SUB    = 2;
constexpr int G_SIZE   = 6;

__global__ __launch_bounds__(256) void SubGroupPooler_59708635349141_kernel(
    const float* __restrict__ P,     // [12, T, D]
    const int*   __restrict__ idx,   // [2, 6] (int32, or int64 pairs -- detected)
    float*       __restrict__ out)   // [T, 2*D]
{
    constexpr int D4  = D_DIM / 4;           // 512 float4 per player-row
    constexpr int Z4  = N_SUB * D4;          // 1024 float4 per output row
    constexpr int TD4 = T_FRAMES * D4;       // float4 per player slab

    const int o4 = blockIdx.x * blockDim.x + threadIdx.x;  // [0, T*Z4)
    const int col4 = o4 & (Z4 - 1);
    const int t    = o4 >> 10;               // o4 / Z4
    const int s    = col4 >> 9;              // col4 / D4  (team)
    const int d4   = col4 & (D4 - 1);

    // Index dtype hedge: if stored as little-endian int64, the int32 view is
    // (lo0,0,lo1,0,...) -> positions 1 and 3 are zero. For int32 arange they
    // are 1 and 3 (nonzero). Wave-uniform branch, negligible cost.
    const bool is64   = (idx[1] == 0) && (idx[3] == 0);
    const int  stride = is64 ? 2 : 1;
    const int* team   = idx + s * G_SIZE * stride;

    const float4* __restrict__ P4 = (const float4*)P;
    const size_t row = (size_t)t * D4 + d4;

    int p0 = team[0];
    float4 m = P4[(size_t)p0 * TD4 + row];
    #pragma unroll
    for (int g = 1; g < G_SIZE; ++g) {
        int p = team[g * stride];
        float4 v = P4[(size_t)p * TD4 + row];
        m.x = fmaxf(m.x, v.x);
        m.y = fmaxf(m.y, v.y);
        m.z = fmaxf(m.z, v.z);
        m.w = fmaxf(m.w, v.w);
    }
    ((float4*)out)[o4] = m;
}

extern "C" void kernel_launch(void* const* d_in, const int* in_sizes, int n_in,
                              void* d_out, int out_size, void* d_ws, size_t ws_size,
                              hipStream_t stream) {
    const float* P   = (const float*)d_in[0];
    const int*   idx = (const int*)d_in[1];
    float*       out = (float*)d_out;

    constexpr int total_f4 = T_FRAMES * N_SUB * D_DIM / 4;  // 4,194,304
    constexpr int block = 256;
    constexpr int grid  = total_f4 / block;                 // 16384

    SubGroupPooler_59708635349141_kernel<<<grid, block, 0, stream>>>(P, idx, out);
}

// Round 3
// 515.121 us; speedup vs baseline: 1.0360x; 1.0360x over previous
//
#include <hip/hip_runtime.h>
#include <hip/hip_bf16.h>

// SubGroupPooler: Z[t, s*D + d] = max_{g in team s} P[idx[s][g], t, d]
// N=12 players, T=4096 frames, D=2048 dims, 2 teams x 6 players.
// Memory-bound: 402.7 MB read + 67.1 MB write -> ~75 us floor at 6.3 TB/s.
//
// R2/R3: one block per frame t (grid=4096). Each thread produces 4 output
// float4s (k=0..3 -> col4 = k*256+tid), so s=k>>1 and d4=(k&1)*256+tid are
// compile-time per unrolled k. All 12 player indices loaded once via wide
// int4 loads (single dependent hop), kept in registers. 24 independent
// dwordx4 loads in flight per thread. Nontemporal loads/stores: zero reuse,
// input (403 MB) > L3 (256 MB). R3 fix: use clang ext_vector_type for the
// nontemporal builtins (HIP float4 is a struct, rejected by the builtin).

constexpr int T_FRAMES = 4096;
constexpr int D_DIM    = 2048;

typedef float  fx4 __attribute__((ext_vector_type(4)));
typedef int    ix4 __attribute__((ext_vector_type(4)));

__global__ __launch_bounds__(256) void SubGroupPooler_59708635349141_kernel(
    const float* __restrict__ P,     // [12, T, D]
    const int*   __restrict__ idx,   // [2, 6] (int32, or int64 pairs -- detected)
    float*       __restrict__ out)   // [T, 2*D]
{
    constexpr int D4  = D_DIM / 4;           // 512 fx4 per player-row
    constexpr int Z4  = 2 * D4;              // 1024 fx4 per output row
    constexpr int TD4 = T_FRAMES * D4;       // fx4 per player slab (2^21)

    const int t   = blockIdx.x;
    const int tid = threadIdx.x;

    // Load all 12 indices with wide loads. int64 detection: LE int64 view of
    // arange has ints (0,0,1,0,...) -> y==w==0; int32 view (0,1,2,3) doesn't.
    // Wave-uniform branch.
    const ix4* idx4 = (const ix4*)idx;
    int p[12];
    {
        ix4 a = idx4[0];
        if (a.y == 0 && a.w == 0) {          // int64 layout: value e at int 2e
            ix4 b = idx4[1], c = idx4[2], d = idx4[3], e = idx4[4], f = idx4[5];
            p[0]=a.x; p[1]=a.z; p[2]=b.x; p[3]=b.z; p[4]=c.x;  p[5]=c.z;
            p[6]=d.x; p[7]=d.z; p[8]=e.x; p[9]=e.z; p[10]=f.x; p[11]=f.z;
        } else {                             // int32 layout
            ix4 b = idx4[1], c = idx4[2];
            p[0]=a.x; p[1]=a.y; p[2]=a.z;  p[3]=a.w;
            p[4]=b.x; p[5]=b.y; p[6]=b.z;  p[7]=b.w;
            p[8]=c.x; p[9]=c.y; p[10]=c.z; p[11]=c.w;
        }
    }

    const fx4* __restrict__ P4   = (const fx4*)P;
    fx4*       __restrict__ out4 = (fx4*)out;
    const int rowbase = t * D4;              // fx4 offset of row t within a slab

    #pragma unroll
    for (int k = 0; k < 4; ++k) {
        const int s  = k >> 1;               // compile-time team per k
        const int d4 = (k & 1) * 256 + tid;  // column within team block
        const int col4 = s * D4 + d4;

        fx4 m = __builtin_nontemporal_load(
            &P4[(size_t)p[s*6 + 0] * TD4 + rowbase + d4]);
        #pragma unroll
        for (int g = 1; g < 6; ++g) {
            fx4 v = __builtin_nontemporal_load(
                &P4[(size_t)p[s*6 + g] * TD4 + rowbase + d4]);
            m.x = fmaxf(m.x, v.x);
            m.y = fmaxf(m.y, v.y);
            m.z = fmaxf(m.z, v.z);
            m.w = fmaxf(m.w, v.w);
        }
        __builtin_nontemporal_store(m, &out4[(size_t)t * Z4 + col4]);
    }
}

extern "C" void kernel_launch(void* const* d_in, const int* in_sizes, int n_in,
                              void* d_out, int out_size, void* d_ws, size_t ws_size,
                              hipStream_t stream) {
    const float* P   = (const float*)d_in[0];
    const int*   idx = (const int*)d_in[1];
    float*       out = (float*)d_out;

    SubGroupPooler_59708635349141_kernel<<<T_FRAMES, 256, 0, stream>>>(P, idx, out);
}